// Round 1
// baseline (365.208 us; speedup 1.0000x reference)
//
#include <hip/hip_runtime.h>

#define EPS 1e-6f

typedef __bf16 bf16x8 __attribute__((ext_vector_type(8)));
typedef __bf16 bf16x4 __attribute__((ext_vector_type(4)));
typedef float fx4 __attribute__((ext_vector_type(4)));

// ---------------- cast kernels ----------------

__global__ __launch_bounds__(256) void cast_f32_bf16(const float* __restrict__ in,
                                                     __bf16* __restrict__ out, int n) {
    int i = (blockIdx.x * 256 + threadIdx.x) * 4;
    if (i >= n) return;
    float4 v = *(const float4*)(in + i);
    bf16x4 o;
    o[0] = (__bf16)v.x; o[1] = (__bf16)v.y; o[2] = (__bf16)v.z; o[3] = (__bf16)v.w;
    *(bf16x4*)(out + i) = o;
}

// W is (Kd x Nd) row-major fp32; WT is (Nd x Kd) bf16
__global__ __launch_bounds__(256) void cast_transpose(const float* __restrict__ W,
                                                      __bf16* __restrict__ WT,
                                                      int Kd, int Nd) {
    int t = blockIdx.x * 256 + threadIdx.x;
    if (t >= Kd * Nd) return;
    int n = t / Kd, k = t % Kd;
    WT[t] = (__bf16)W[(size_t)k * Nd + n];
}

// ---------------- GEMM + bias + ELU (bf16 in, bf16 out) ----------------
// X: (M x K) bf16 row-major, WT: (N x K) bf16 row-major, H: (M x N) bf16
// block tile 64x64, K-step 32, 256 threads = 4 waves, wave w owns rows [w*16, w*16+16)
__global__ __launch_bounds__(256) void gemm_bias_elu(const __bf16* __restrict__ X,
                                                     const __bf16* __restrict__ WT,
                                                     const float* __restrict__ bias,
                                                     __bf16* __restrict__ H,
                                                     int N, int K) {
    __shared__ __align__(16) __bf16 As[64][40];
    __shared__ __align__(16) __bf16 Bs[64][40];
    int tid  = threadIdx.x;
    int wave = tid >> 6, lane = tid & 63;
    int m0 = blockIdx.y * 64, n0 = blockIdx.x * 64;
    int lrow = tid >> 2;          // 0..63
    int lkof = (tid & 3) * 8;     // 0,8,16,24

    fx4 acc[4] = {fx4{0,0,0,0}, fx4{0,0,0,0}, fx4{0,0,0,0}, fx4{0,0,0,0}};
    int quad = lane >> 4;
    int col  = lane & 15;
    int mrow = wave * 16 + col;

    for (int k0 = 0; k0 < K; k0 += 32) {
        bf16x8 av = *(const bf16x8*)(X  + (size_t)(m0 + lrow) * K + k0 + lkof);
        bf16x8 bv = *(const bf16x8*)(WT + (size_t)(n0 + lrow) * K + k0 + lkof);
        __syncthreads();
        *(bf16x8*)&As[lrow][lkof] = av;
        *(bf16x8*)&Bs[lrow][lkof] = bv;
        __syncthreads();
        bf16x8 a = *(const bf16x8*)&As[mrow][quad * 8];
#pragma unroll
        for (int nt = 0; nt < 4; nt++) {
            bf16x8 b = *(const bf16x8*)&Bs[nt * 16 + col][quad * 8];
            acc[nt] = __builtin_amdgcn_mfma_f32_16x16x32_bf16(a, b, acc[nt], 0, 0, 0);
        }
    }
    // epilogue: C[m][n], m = quad*4 + r (per wave block), n = nt*16 + col
#pragma unroll
    for (int nt = 0; nt < 4; nt++) {
        int n = n0 + nt * 16 + col;
        float bn = bias[n];
#pragma unroll
        for (int r = 0; r < 4; r++) {
            int m = m0 + wave * 16 + quad * 4 + r;
            float v = acc[nt][r] + bn;
            v = v > 0.f ? v : expm1f(v);
            H[(size_t)m * N + n] = (__bf16)v;
        }
    }
}

// ---------------- LayerNorm (ddof=1), in-place on bf16 ----------------
__global__ __launch_bounds__(256) void ln_kernel(__bf16* __restrict__ H,
                                                 const float* __restrict__ g,
                                                 const float* __restrict__ be, int N) {
    int row = blockIdx.x;
    __bf16* x = H + (size_t)row * N;
    int tid = threadIdx.x;
    float s = 0.f, s2 = 0.f;
    for (int i = tid; i < N; i += 256) { float v = (float)x[i]; s += v; s2 += v * v; }
#pragma unroll
    for (int off = 32; off >= 1; off >>= 1) {
        s  += __shfl_down(s, off, 64);
        s2 += __shfl_down(s2, off, 64);
    }
    __shared__ float sh[8];
    if ((tid & 63) == 0) { sh[tid >> 6] = s; sh[(tid >> 6) + 4] = s2; }
    __syncthreads();
    s  = sh[0] + sh[1] + sh[2] + sh[3];
    s2 = sh[4] + sh[5] + sh[6] + sh[7];
    float mu  = s / N;
    float var = (s2 - N * mu * mu) / (N - 1);
    var = fmaxf(var, 0.f);
    float inv = 1.f / (sqrtf(var) + EPS);
    for (int i = tid; i < N; i += 256) {
        float v = (float)x[i];
        x[i] = (__bf16)(g[i] * (v - mu) * inv + be[i]);
    }
}

// ---------------- routing: logits + softmax over B ----------------
__global__ __launch_bounds__(256) void routing_kernel(const __bf16* __restrict__ H3,
                                                      const float* __restrict__ Wout,
                                                      const float* __restrict__ bout,
                                                      float* __restrict__ routing) {
    int e = blockIdx.x;
    int tid = threadIdx.x;  // = b
    const bf16x8* xv = (const bf16x8*)(H3 + ((size_t)e * 256 + tid) * 128);
    float l = 0.f;
#pragma unroll
    for (int jj = 0; jj < 16; jj++) {
        bf16x8 v = xv[jj];
#pragma unroll
        for (int j = 0; j < 8; j++) l += (float)v[j] * Wout[jj * 8 + j];
    }
    l += bout[0];
    __shared__ float sh[4];
    float m = l;
#pragma unroll
    for (int off = 32; off >= 1; off >>= 1) m = fmaxf(m, __shfl_down(m, off, 64));
    if ((tid & 63) == 0) sh[tid >> 6] = m;
    __syncthreads();
    m = fmaxf(fmaxf(sh[0], sh[1]), fmaxf(sh[2], sh[3]));
    __syncthreads();
    float ex = __expf(l - m);
    float ssum = ex;
#pragma unroll
    for (int off = 32; off >= 1; off >>= 1) ssum += __shfl_down(ssum, off, 64);
    if ((tid & 63) == 0) sh[tid >> 6] = ssum;
    __syncthreads();
    ssum = sh[0] + sh[1] + sh[2] + sh[3];
    routing[e * 256 + tid] = ex / ssum;
}

// ---------------- output: gather-style scatter into (B, V+1, 2) ----------------
// idx = k*12 + off (off in [0,12)): bin per k is disjoint. Thread per (b, kbin).
#define VV 50257
#define KK 4097
#define NBIN 4189  // ceil(50257/12)

__global__ __launch_bounds__(256) void scatter_kernel(const float2* __restrict__ pred,
                                                      const float* __restrict__ routing,
                                                      float* __restrict__ out) {
    int b  = blockIdx.y;
    int kb = blockIdx.x * 256 + threadIdx.x;
    __shared__ float rsh[16];
    if (threadIdx.x < 16) rsh[threadIdx.x] = routing[threadIdx.x * 256 + b];
    __syncthreads();
    if (kb >= NBIN) return;

    float bins[12];
#pragma unroll
    for (int r = 0; r < 12; r++) bins[r] = 0.f;

    if (kb < 4096) {
#pragma unroll
        for (int e = 0; e < 16; e++) {
            float2 p = pred[(size_t)(e * 256 + b) * KK + kb];
            int r = (int)p.y - kb * 12;
            float val = rsh[e] * p.x;
#pragma unroll
            for (int rr = 0; rr < 12; rr++)
                if (rr == r) bins[rr] += val;
        }
    }
    float2* orow = (float2*)out + (size_t)b * (VV + 1);
    int vbase = kb * 12;
#pragma unroll
    for (int r = 0; r < 12; r++) {
        int v = vbase + r;
        if (v < VV) orow[v] = make_float2(bins[r], (float)v);
    }
    if (kb == NBIN - 1) orow[VV] = make_float2(0.f, -1.f);
}

// ---------------- launch ----------------

extern "C" void kernel_launch(void* const* d_in, const int* in_sizes, int n_in,
                              void* d_out, int out_size, void* d_ws, size_t ws_size,
                              hipStream_t stream) {
    const float*  emb  = (const float*)d_in[0];
    const float2* pred = (const float2*)d_in[1];
    const float* W1 = (const float*)d_in[2];
    const float* b1 = (const float*)d_in[3];
    const float* g1 = (const float*)d_in[4];
    const float* be1 = (const float*)d_in[5];
    const float* W2 = (const float*)d_in[6];
    const float* b2 = (const float*)d_in[7];
    const float* g2 = (const float*)d_in[8];
    const float* be2 = (const float*)d_in[9];
    const float* W3 = (const float*)d_in[10];
    const float* b3 = (const float*)d_in[11];
    const float* g3 = (const float*)d_in[12];
    const float* be3 = (const float*)d_in[13];
    const float* Wout = (const float*)d_in[14];
    const float* bout = (const float*)d_in[15];

    char* ws = (char*)d_ws;
    __bf16* W1T = (__bf16*)ws;            ws += 512 * 1024 * 2;
    __bf16* W2T = (__bf16*)ws;            ws += 256 * 512 * 2;
    __bf16* W3T = (__bf16*)ws;            ws += 128 * 256 * 2;
    __bf16* X0  = (__bf16*)ws;            ws += (size_t)4096 * 1024 * 2;
    __bf16* H1  = (__bf16*)ws;            ws += (size_t)4096 * 512 * 2;
    __bf16* H2  = (__bf16*)ws;            ws += (size_t)4096 * 256 * 2;
    __bf16* H3  = (__bf16*)ws;            ws += (size_t)4096 * 128 * 2;
    float*  routing = (float*)ws;         ws += 4096 * 4;

    cast_transpose<<<(512 * 1024 + 255) / 256, 256, 0, stream>>>(W1, W1T, 1024, 512);
    cast_transpose<<<(256 * 512 + 255) / 256, 256, 0, stream>>>(W2, W2T, 512, 256);
    cast_transpose<<<(128 * 256 + 255) / 256, 256, 0, stream>>>(W3, W3T, 256, 128);
    cast_f32_bf16<<<4096, 256, 0, stream>>>(emb, X0, 4096 * 1024);

    gemm_bias_elu<<<dim3(8, 64), 256, 0, stream>>>(X0, W1T, b1, H1, 512, 1024);
    ln_kernel<<<4096, 256, 0, stream>>>(H1, g1, be1, 512);
    gemm_bias_elu<<<dim3(4, 64), 256, 0, stream>>>(H1, W2T, b2, H2, 256, 512);
    ln_kernel<<<4096, 256, 0, stream>>>(H2, g2, be2, 256);
    gemm_bias_elu<<<dim3(2, 64), 256, 0, stream>>>(H2, W3T, b3, H3, 128, 256);
    ln_kernel<<<4096, 256, 0, stream>>>(H3, g3, be3, 128);

    routing_kernel<<<16, 256, 0, stream>>>(H3, Wout, bout, routing);
    scatter_kernel<<<dim3((NBIN + 255) / 256, 256), 256, 0, stream>>>(pred, routing, (float*)d_out);
}